// Round 4
// baseline (723.556 us; speedup 1.0000x reference)
//
#include <hip/hip_runtime.h>
#include <hip/hip_bf16.h>

// MLA forward, round 10:
//  - attention rewritten: 4 waves x 32 q-rows (128/block), 32x32x16 MFMA.
//    Halves per-row LDS K-traffic; P-transpose done in-register via
//    shfl_xor(32) (no LDS pt); single-buffered 45 KB LDS -> 2 blocks/CU.
//  - kv-projection: f32 gemm_nt replaced by 3 bf16-MFMA passes
//    (xhi@whi + xlo@whi + xhi@wlo, f32 global accumulate) ~= f32 accuracy.
//    Buffers alias dead workspace (xlo=ovb slot, wa_hi/lo=wqb after q-proj).
// B=2 S=2048 D=2048 H=16 NOPE=128 ROPE=64 V=128 C=512
#define B_ 2
#define S_ 2048
#define H_ 16

typedef unsigned short ushort_t;
typedef unsigned int uint_t;
typedef __attribute__((ext_vector_type(8))) short bf16x8;
typedef __attribute__((ext_vector_type(4))) float f32x4;
typedef __attribute__((ext_vector_type(16))) float f32x16;

__device__ __forceinline__ ushort_t f2bf(float f) {
    uint_t u = __float_as_uint(f);
    return (ushort_t)((u + 0x7fffu + ((u >> 16) & 1u)) >> 16);
}
__device__ __forceinline__ float bf2f(ushort_t v) {
    return __uint_as_float(((uint_t)v) << 16);
}

// global -> LDS direct copy, 16B per lane. LDS dest wave-uniform; HW writes
// lane i at ldsbase + i*16. Global src per-lane.
__device__ __forceinline__ void gl_lds16(const ushort_t* g, ushort_t* l) {
    __builtin_amdgcn_global_load_lds(
        (const __attribute__((address_space(1))) unsigned int*)(unsigned long long)g,
        (__attribute__((address_space(3))) unsigned int*)(unsigned int)(unsigned long long)l,
        16, 0, 0);
}

// ---------------------------------------------------------------------------
// f32 -> bf16 cast
// ---------------------------------------------------------------------------
__global__ __launch_bounds__(256) void cast_bf16(const float* __restrict__ src,
                                                 ushort_t* __restrict__ dst, int n)
{
    int i = (blockIdx.x * 256 + threadIdx.x) * 4;
    if (i < n) {
        float4 v = *(const float4*)(src + i);
        ushort_t pk[4] = { f2bf(v.x), f2bf(v.y), f2bf(v.z), f2bf(v.w) };
        *(uint2*)(dst + i) = *(const uint2*)pk;
    }
}

// f32 -> bf16 hi + bf16 lo (residual) split cast
__global__ __launch_bounds__(256) void cast2_bf16(const float* __restrict__ src,
                                                  ushort_t* __restrict__ hi,
                                                  ushort_t* __restrict__ lo, int n)
{
    int i = (blockIdx.x * 256 + threadIdx.x) * 4;
    if (i < n) {
        float4 v = *(const float4*)(src + i);
        float vv[4] = { v.x, v.y, v.z, v.w };
        ushort_t ph[4], pl[4];
#pragma unroll
        for (int k = 0; k < 4; k++) {
            ph[k] = f2bf(vv[k]);
            pl[k] = f2bf(vv[k] - bf2f(ph[k]));
        }
        *(uint2*)(hi + i) = *(const uint2*)ph;
        *(uint2*)(lo + i) = *(const uint2*)pl;
    }
}

// ---------------------------------------------------------------------------
// bf16 MFMA GEMM (m97-style): C[M,N] = A[M,K] @ B[N,K]^T. M%128==0, N%128==0
// (tiling), K%64==0. Nreal guards B-row reads and C stores; ldc = C stride.
// mode: 0 = f32 store, 1 = bf16 store, 2 = f32 accumulate.
// ---------------------------------------------------------------------------
__global__ __launch_bounds__(256, 2) void gemm_bf16(const ushort_t* __restrict__ A,
                                                    const ushort_t* __restrict__ Bm,
                                                    float* __restrict__ Cf,
                                                    ushort_t* __restrict__ Cb,
                                                    int M, int N, int K,
                                                    int ldc, int Nreal, int mode)
{
    __shared__ __align__(16) ushort_t As[2][8192];
    __shared__ __align__(16) ushort_t Bs[2][8192];
    const int tid = threadIdx.x;
    const int wv = tid >> 6, lane = tid & 63, l16 = lane & 15, quad = lane >> 4;
    const int wm = wv >> 1, wn = wv & 1;
    const int m0 = blockIdx.y * 128, n0 = blockIdx.x * 128;
    const int srow = lane >> 3;                  // 0..7 within 8-row chunk
    const int sch  = ((lane & 7) ^ srow) * 8;    // swizzled source chunk (ushorts)

    f32x4 acc[16];
#pragma unroll
    for (int i = 0; i < 16; i++) acc[i] = (f32x4)(0.f);

    // prologue: stage k0=0 into buf 0
#pragma unroll
    for (int p = 0; p < 4; p++) {
        int g = wv + p*4, row = g*8 + srow;
        int rowb = n0 + row; if (rowb > Nreal - 1) rowb = Nreal - 1;
        gl_lds16(A  + (size_t)(m0 + row) * K + sch, &As[0][g*512]);
        gl_lds16(Bm + (size_t)rowb * K + sch,       &Bs[0][g*512]);
    }
    __syncthreads();

    int cur = 0;
    for (int k0 = 0; k0 < K; k0 += 64) {
        if (k0 + 64 < K) {
#pragma unroll
            for (int p = 0; p < 4; p++) {
                int g = wv + p*4, row = g*8 + srow;
                int rowb = n0 + row; if (rowb > Nreal - 1) rowb = Nreal - 1;
                gl_lds16(A  + (size_t)(m0 + row) * K + k0 + 64 + sch, &As[cur^1][g*512]);
                gl_lds16(Bm + (size_t)rowb * K + k0 + 64 + sch,       &Bs[cur^1][g*512]);
            }
        }
#pragma unroll
        for (int ks = 0; ks < 2; ks++) {
            bf16x8 af[4], bfr[4];
#pragma unroll
            for (int mt = 0; mt < 4; mt++) {
                int row = wm*64 + mt*16 + l16;
                af[mt] = *(const bf16x8*)(&As[cur][row*64 + (((ks*4+quad) ^ (l16&7))*8)]);
            }
#pragma unroll
            for (int nt = 0; nt < 4; nt++) {
                int row = wn*64 + nt*16 + l16;
                bfr[nt] = *(const bf16x8*)(&Bs[cur][row*64 + (((ks*4+quad) ^ (l16&7))*8)]);
            }
#pragma unroll
            for (int mt = 0; mt < 4; mt++)
#pragma unroll
                for (int nt = 0; nt < 4; nt++)
                    acc[mt*4+nt] = __builtin_amdgcn_mfma_f32_16x16x32_bf16(af[mt], bfr[nt], acc[mt*4+nt], 0, 0, 0);
        }
        __syncthreads();
        cur ^= 1;
    }
#pragma unroll
    for (int mt = 0; mt < 4; mt++)
#pragma unroll
        for (int nt = 0; nt < 4; nt++) {
            int cc = n0 + wn*64 + nt*16 + l16;
            if (cc < Nreal) {
#pragma unroll
                for (int r = 0; r < 4; r++) {
                    size_t rr = m0 + wm*64 + mt*16 + quad*4 + r;
                    float v = acc[mt*4+nt][r];
                    if (mode == 1)      Cb[rr*ldc + cc] = f2bf(v);
                    else if (mode == 2) Cf[rr*ldc + cc] += v;
                    else                Cf[rr*ldc + cc] = v;
                }
            }
        }
}

// ---------------------------------------------------------------------------
// V' GEMM: vpT[b][h][c][t] = sum_k kvn[b,t,k] * wbv[h,c,k]. Tile 128x128, K=512.
// ---------------------------------------------------------------------------
__global__ __launch_bounds__(256, 2) void gemm_vp(const ushort_t* __restrict__ kvnb,
                                                  const ushort_t* __restrict__ wbvB,
                                                  ushort_t* __restrict__ vpT)
{
    __shared__ __align__(16) ushort_t As[2][8192];
    __shared__ __align__(16) ushort_t Bs[2][8192];
    const int tid = threadIdx.x;
    const int wv = tid >> 6, lane = tid & 63, l16 = lane & 15, quad = lane >> 4;
    const int wm = wv >> 1, wn = wv & 1;
    const int m0 = blockIdx.x * 128;
    const int h  = blockIdx.y;
    const ushort_t* Bh = wbvB + h*65536;
    const int srow = lane >> 3;
    const int sch  = ((lane & 7) ^ srow) * 8;

    f32x4 acc[16];
#pragma unroll
    for (int i = 0; i < 16; i++) acc[i] = (f32x4)(0.f);

#pragma unroll
    for (int p = 0; p < 4; p++) {
        int g = wv + p*4, row = g*8 + srow;
        gl_lds16(kvnb + (size_t)(m0 + row)*512 + sch, &As[0][g*512]);
        gl_lds16(Bh   + (size_t)row*512 + sch,        &Bs[0][g*512]);
    }
    __syncthreads();

    int cur = 0;
    for (int k0 = 0; k0 < 512; k0 += 64) {
        if (k0 + 64 < 512) {
#pragma unroll
            for (int p = 0; p < 4; p++) {
                int g = wv + p*4, row = g*8 + srow;
                gl_lds16(kvnb + (size_t)(m0 + row)*512 + k0 + 64 + sch, &As[cur^1][g*512]);
                gl_lds16(Bh   + (size_t)row*512 + k0 + 64 + sch,        &Bs[cur^1][g*512]);
            }
        }
#pragma unroll
        for (int ks = 0; ks < 2; ks++) {
            bf16x8 af[4], bfr[4];
#pragma unroll
            for (int mt = 0; mt < 4; mt++) {
                int row = wm*64 + mt*16 + l16;
                af[mt] = *(const bf16x8*)(&As[cur][row*64 + (((ks*4+quad) ^ (l16&7))*8)]);
            }
#pragma unroll
            for (int nt = 0; nt < 4; nt++) {
                int row = wn*64 + nt*16 + l16;
                bfr[nt] = *(const bf16x8*)(&Bs[cur][row*64 + (((ks*4+quad) ^ (l16&7))*8)]);
            }
#pragma unroll
            for (int mt = 0; mt < 4; mt++)
#pragma unroll
                for (int nt = 0; nt < 4; nt++)
                    acc[mt*4+nt] = __builtin_amdgcn_mfma_f32_16x16x32_bf16(af[mt], bfr[nt], acc[mt*4+nt], 0, 0, 0);
        }
        __syncthreads();
        cur ^= 1;
    }
    // scatter: 4 consecutive t per lane -> uint2
#pragma unroll
    for (int mt = 0; mt < 4; mt++)
#pragma unroll
        for (int nt = 0; nt < 4; nt++) {
            int rr = m0 + wm*64 + mt*16 + quad*4;
            int bb = rr >> 11, t = rr & 2047;
            int cc = wn*64 + nt*16 + l16;
            ushort_t pk[4];
#pragma unroll
            for (int r = 0; r < 4; r++) pk[r] = f2bf(acc[mt*4+nt][r]);
            *(uint2*)(vpT + ((size_t)((bb*16 + h)*128 + cc))*2048 + t) = *(const uint2*)pk;
        }
}

// ---------------------------------------------------------------------------
__global__ __launch_bounds__(256) void prep_wb(const float* __restrict__ wkv_b,
                                               ushort_t* __restrict__ wbkT,
                                               ushort_t* __restrict__ wbvB)
{
    int u = blockIdx.x * 256 + threadIdx.x;
    {
        int h = u >> 16, rem = u & 65535, c = rem >> 7, d = rem & 127;
        wbkT[u] = f2bf(wkv_b[h*131072 + d*512 + c]);
    }
    {
        int h = u >> 16, rem = u & 65535;
        wbvB[u] = f2bf(wkv_b[h*131072 + 65536 + rem]);
    }
}

// ---------------------------------------------------------------------------
__global__ __launch_bounds__(256) void kv_norm_rope(const float* __restrict__ kvr,
                                                    const float* __restrict__ w,
                                                    const float* __restrict__ cosT,
                                                    const float* __restrict__ sinT,
                                                    ushort_t* __restrict__ kvnb,
                                                    ushort_t* __restrict__ kpeb)
{
    const int bs   = blockIdx.x * 4 + (threadIdx.x >> 6);
    const int lane = threadIdx.x & 63;
    const int s    = bs & (S_ - 1);
    const float* row = kvr + bs * 576;

    float4 v0 = *(const float4*)(row + lane*8);
    float4 v1 = *(const float4*)(row + lane*8 + 4);
    float ss = v0.x*v0.x + v0.y*v0.y + v0.z*v0.z + v0.w*v0.w
             + v1.x*v1.x + v1.y*v1.y + v1.z*v1.z + v1.w*v1.w;
#pragma unroll
    for (int off = 32; off >= 1; off >>= 1) ss += __shfl_xor(ss, off);
    const float rs = rsqrtf(ss * (1.0f/512.0f) + 1e-6f);

    float4 w0 = *(const float4*)(w + lane*8);
    float4 w1 = *(const float4*)(w + lane*8 + 4);
    float o[8];
    o[0] = v0.x*rs*w0.x; o[1] = v0.y*rs*w0.y; o[2] = v0.z*rs*w0.z; o[3] = v0.w*rs*w0.w;
    o[4] = v1.x*rs*w1.x; o[5] = v1.y*rs*w1.y; o[6] = v1.z*rs*w1.z; o[7] = v1.w*rs*w1.w;

    ushort_t pk[8];
#pragma unroll
    for (int p = 0; p < 8; p++) pk[p] = f2bf(o[p]);
    *(uint4*)(kvnb + (size_t)bs*512 + lane*8) = *(const uint4*)pk;

    if (lane < 32) {
        float xr = row[512 + 2*lane], xi = row[512 + 2*lane + 1];
        float c  = cosT[s*32 + lane], sn = sinT[s*32 + lane];
        ushort_t p2[2] = { f2bf(xr*c - xi*sn), f2bf(xr*sn + xi*c) };
        *(uint_t*)(kpeb + (size_t)bs*64 + 2*lane) = *(const uint_t*)p2;
    }
}

// ---------------------------------------------------------------------------
// MFMA flash attention v8: 4 waves x 32 q-rows, 32x32x16 MFMA, TK=32,
// single-buffered LDS (45 KB -> 2 blocks/CU), in-register P transpose.
// ---------------------------------------------------------------------------
__global__ __launch_bounds__(256, 2) void attn_mfma(
    const ushort_t* __restrict__ qb,
    const ushort_t* __restrict__ kvnb,
    const ushort_t* __restrict__ kpeb,
    const ushort_t* __restrict__ vpT,
    const float* __restrict__ cosT,
    const float* __restrict__ sinT,
    const ushort_t* __restrict__ wbkT,
    ushort_t* __restrict__ ovb)
{
    // XCD/LPT swizzle: batch = flat&1, longest causal blocks first
    const int flat = blockIdx.x + 16*blockIdx.y + 256*blockIdx.z;
    const int b    = flat & 1;
    const int rem  = flat >> 1;
    const int h    = rem & 15;
    const int q0   = (15 - (rem >> 4)) << 7;

    const int tid  = threadIdx.x;
    const int w    = tid >> 6;       // 0..3
    const int lane = tid & 63;
    const int q5   = lane & 31;
    const int hi   = lane >> 5;
    const int h8   = hi * 8;
    const float scale = 0.07216878364870323f;   // 192^-0.5

    // LDS: F = 36 groups x 1KB (K-tile frags), V = 8 groups x 1KB (V'-tile)
    // phase-A scratch overlays F (per wave 32x136 ushorts), dead before loop.
    __shared__ __align__(16) ushort_t lds[22528];   // 45056 B
    ushort_t* F = lds;
    ushort_t* V = lds + 18432;

    const ushort_t* kvn_b = kvnb + (size_t)b*S_*512;
    const ushort_t* kpe_b = kpeb + (size_t)b*S_*64;
    const ushort_t* vpT_h = vpT + (size_t)(b*16 + h)*128*2048;

    const int r0w = q0 + w*32;
    const int rq  = r0w + q5;       // this lane's q-row (as q5)

    // ===== phase A: qf[36] = B-frags of (q_abs | rope(q_pe)) * scale
    bf16x8 qf[36];
    {
        const ushort_t* qrow = qb + (size_t)(b*S_ + rq)*3072 + h*192;
        bf16x8 qa[8];
#pragma unroll
        for (int ks = 0; ks < 8; ks++)
            qa[ks] = *(const bf16x8*)(qrow + ks*16 + h8);

        ushort_t* scrw = lds + w*4352;     // 32 x 136 per wave
        const ushort_t* wbk_h = wbkT + h*65536;
#pragma unroll
        for (int qq = 0; qq < 4; qq++) {
            f32x16 ab[4];
#pragma unroll
            for (int cb = 0; cb < 4; cb++) ab[cb] = (f32x16)(0.f);
#pragma unroll
            for (int cb = 0; cb < 4; cb++) {
                const ushort_t* wp = wbk_h + (size_t)(qq*128 + cb*32 + q5)*128 + h8;
#pragma unroll
                for (int ks = 0; ks < 8; ks++) {
                    bf16x8 bw = *(const bf16x8*)(wp + ks*16);
                    ab[cb] = __builtin_amdgcn_mfma_f32_32x32x16_bf16(qa[ks], bw, ab[cb], 0, 0, 0);
                }
            }
            asm volatile("" ::: "memory");
#pragma unroll
            for (int cb = 0; cb < 4; cb++)
#pragma unroll
                for (int r = 0; r < 16; r++)
                    scrw[((r&3) + 8*(r>>2) + 4*hi)*136 + cb*32 + q5] = f2bf(ab[cb][r] * scale);
            asm volatile("" ::: "memory");
#pragma unroll
            for (int gg = 0; gg < 8; gg++)
                qf[qq*8 + gg] = *(const bf16x8*)(scrw + q5*136 + gg*16 + h8);
            asm volatile("" ::: "memory");
        }
        // pe -> qf[32..35], computed per-lane (q = q5, dims hi*8..)
#pragma unroll
        for (int gg = 0; gg < 4; gg++) {
            uint4 pv4 = *(const uint4*)(qrow + 128 + gg*16 + h8);
            const ushort_t* pe = (const ushort_t*)&pv4;
            ushort_t pk[8];
#pragma unroll
            for (int u2 = 0; u2 < 4; u2++) {
                float xr = bf2f(pe[2*u2]), xi = bf2f(pe[2*u2+1]);
                int pi = gg*8 + hi*4 + u2;
                float c = cosT[rq*32 + pi], sn = sinT[rq*32 + pi];
                pk[2*u2]   = f2bf((xr*c  - xi*sn) * scale);
                pk[2*u2+1] = f2bf((xr*sn + xi*c ) * scale);
            }
            qf[32 + gg] = *(const bf16x8*)pk;
        }
    }
    __syncthreads();   // phase-A scratch dead before staging

    // ===== flash main loop: TK=32, single buffer, 2 barriers/tile =====
    f32x16 o[4];
#pragma unroll
    for (int nc = 0; nc < 4; nc++) o[nc] = (f32x16)(0.f);
    float m_s = -1e30f, l_s = 0.f;

    const int bniter = (q0 >> 5) + 4;       // block-uniform
    const int wniter = (r0w >> 5) + 1;      // this wave's causal bound

#pragma unroll 1
    for (int it = 0; it < bniter; it++) {
        const int t0 = it * 32;
        // stage: 9 F groups + 2 V groups per wave
#pragma unroll
        for (int ii = 0; ii < 9; ii++) {
            int g = w + ii*4;
            const ushort_t* src = (g < 32)
                ? (kvn_b + (size_t)(t0 + q5)*512 + g*16 + h8)
                : (kpe_b + (size_t)(t0 + q5)*64 + (g-32)*16 + h8);
            gl_lds16(src, F + g*512);
        }
#pragma unroll
        for (int ii = 0; ii < 2; ii++) {
            int gv = w + ii*4;
            const ushort_t* src = vpT_h + (size_t)((gv>>1)*32 + q5)*2048 + t0 + (gv&1)*16 + h8;
            gl_lds16(src, V + gv*512);
        }
        __syncthreads();   // staged data visible (vmcnt drained)

        if (it < wniter) {
            // S^T: C[t][q], one 32x32 tile, k-chain over 576 dims
            f32x16 s = (f32x16)(0.f);
#pragma unroll
            for (int g = 0; g < 36; g++) {
                bf16x8 kf = *(const bf16x8*)(F + g*512 + lane*8);
                s = __builtin_amdgcn_mfma_f32_32x32x16_bf16(kf, qf[g], s, 0, 0, 0);
            }
            // softmax for q-row rq; lane holds 16 t's: (r&3)+8*(r>>2)+4*hi
            float mx = -1e30f;
#pragma unroll
            for (int r = 0; r < 16; r++) {
                bool ok = (t0 + (r&3) + 8*(r>>2) + 4*hi) <= rq;
                s[r] = ok ? s[r] : -1e30f;
                mx = fmaxf(mx, s[r]);
            }
            mx = fmaxf(mx, __shfl_xor(mx, 32));
            if (!__all(mx <= m_s)) {        // exact skip when max unchanged
                float mn = fmaxf(m_s, mx);
                float al = __expf(m_s - mn);
                m_s = mn; l_s *= al;
#pragma unroll
                for (int r = 0; r < 16; r++) {
                    float a = __shfl(al, (r&3) + 8*(r>>2) + 4*hi);
#pragma unroll
                    for (int nc = 0; nc < 4; nc++) o[nc][r] = o[nc][r] * a;
                }
            }
            float ps = 0.f;
#pragma unroll
            for (int r = 0; r < 16; r++) {
                s[r] = (s[r] > -1e29f) ? __expf(s[r] - m_s) : 0.f;
                ps += s[r];
            }
            ps += __shfl_xor(ps, 32);
            l_s += ps;

            // P -> bf16 pairs; in-register transpose to A-frags via shfl_xor(32)
            uint_t u[8];
#pragma unroll
            for (int m = 0; m < 8; m++)
                u[m] = (uint_t)f2bf(s[2*m]) | ((uint_t)f2bf(s[2*m+1]) << 16);
#pragma unroll
            for (int kt = 0; kt < 2; kt++) {
                uint_t sw0 = (uint_t)__shfl_xor((int)u[4*kt+0], 32);
                uint_t sw1 = (uint_t)__shfl_xor((int)u[4*kt+1], 32);
                uint_t sw2 = (uint_t)__shfl_xor((int)u[4*kt+2], 32);
                uint_t sw3 = (uint_t)__shfl_xor((int)u[4*kt+3], 32);
                uint4 aw;
                aw.x = hi ? sw2 : u[4*kt+0];
                aw.y = hi ? sw3 : u[4*kt+1];
                aw.z = hi ? u[4*kt+2] : sw0;
                aw.w = hi ? u[4*kt+3] : sw1;
                bf16x8 ap = *(const bf16x8*)&aw;
#pragma unroll
                for (int nc = 0; nc < 4; nc++) {
                    bf16x8 bv = *(const bf16x8*)(V + (nc*2 + kt)*512 + lane*8);
                    o[nc] = __builtin_amdgcn_mfma_f32_32x32x16_bf16(ap, bv, o[nc], 0, 0, 0);
                }
            }
        }
        __syncthreads();   // reads done before next stage overwrites
    }

    // ===== output: ovb = o / l =====
    float linv = 1.f / l_s;
#pragma unroll
    for (int r = 0; r < 16; r++) {
        float a = __shfl(linv, (r&3) + 8*(r>>2) + 4*hi);
        size_t row = (size_t)(b*S_ + r0w + (r&3) + 8*(r>>2) + 4*hi);
#pragma unroll
        for (int nc = 0; nc < 4; nc++)
            ovb[row*2048 + h*128 + nc*32 + q5] = f2bf(o[nc][r] * a);
    }
}

// ---------------------------------------------------------------------------
extern "C" void kernel_launch(void* const* d_in, const int* in_sizes, int n_in,
                              void* d_out, int out_size, void* d_ws, size_t ws_size,
                              hipStream_t stream) {
    const float* x     = (const float*)d_in[0];
    const float* cosT  = (const float*)d_in[1];
    const float* sinT  = (const float*)d_in[2];
    // d_in[3] mask: unused (causality applied directly)
    const float* wq    = (const float*)d_in[4];
    const float* wkv_a = (const float*)d_in[5];
    const float* kvw   = (const float*)d_in[6];
    const float* wkv_b = (const float*)d_in[7];
    const float* wo    = (const float*)d_in[8];
    float* out = (float*)d_out;

    ushort_t* qb   = (ushort_t*)d_ws;       // 4096x3072 bf16
    ushort_t* xb   = qb   + 12582912;       // 4096x2048 x-hi; later vpT
    ushort_t* wqb  = xb   + 8388608;        // 3072x2048; later wa_hi/wa_lo
    ushort_t* wob  = wqb  + 6291456;        // 2048x2048
    ushort_t* ovb  = wob  + 4194304;        // x-lo early; attn output later
    ushort_t* kvnb = ovb  + 8388608;        // 4096x512
    ushort_t* kpeb = kvnb + 2097152;        // 4096x64
    ushort_t* kvnT = kpeb + 262144;         // unused slot
    ushort_t* wbkT = kvnT + 2097152;        // 16x512x128
    ushort_t* wbvB = wbkT + 1048576;        // 16x128x512
    float*    kvr  = (float*)(wbvB + 1048576);  // 4096x576 f32

    ushort_t* xlo  = ovb;                   // 4096x2048 bf16 (dead until attn)
    ushort_t* wahi = wqb;                   // 576x2048 bf16 (after q-proj)
    ushort_t* walo = wqb + 1179648;         // 576x2048 bf16
    ushort_t* vpT  = xb;                    // 2x16x128x2048 bf16 (after kv gemms)

    dim3 blk(256);
    cast2_bf16<<<dim3(8192), blk, 0, stream>>>(x, xb, xlo, 8388608);
    cast_bf16<<<dim3(6144), blk, 0, stream>>>(wq, wqb, 6291456);
    cast_bf16<<<dim3(4096), blk, 0, stream>>>(wo, wob, 4194304);
    prep_wb<<<dim3(4096), blk, 0, stream>>>(wkv_b, wbkT, wbvB);
    gemm_bf16<<<dim3(24, 32), blk, 0, stream>>>(xb, wqb, nullptr, qb, 4096, 3072, 2048, 3072, 3072, 1);
    cast2_bf16<<<dim3(1152), blk, 0, stream>>>(wkv_a, wahi, walo, 1179648);
    gemm_bf16<<<dim3(5, 32), blk, 0, stream>>>(xb,  wahi, kvr, nullptr, 4096, 640, 2048, 576, 576, 0);
    gemm_bf16<<<dim3(5, 32), blk, 0, stream>>>(xlo, wahi, kvr, nullptr, 4096, 640, 2048, 576, 576, 2);
    gemm_bf16<<<dim3(5, 32), blk, 0, stream>>>(xb,  walo, kvr, nullptr, 4096, 640, 2048, 576, 576, 2);
    kv_norm_rope<<<dim3(1024), blk, 0, stream>>>(kvr, kvw, cosT, sinT, kvnb, kpeb);
    gemm_vp<<<dim3(32, 16), blk, 0, stream>>>(kvnb, wbvB, vpT);
    attn_mfma<<<dim3(16, 16, 2), blk, 0, stream>>>(qb, kvnb, kpeb, vpT, cosT, sinT, wbkT, ovb);
    gemm_bf16<<<dim3(16, 32), blk, 0, stream>>>(ovb, wob, out, nullptr, 4096, 2048, 2048, 2048, 2048, 0);
}